// Round 3
// baseline (469.886 us; speedup 1.0000x reference)
//
#include <hip/hip_runtime.h>
#include <stdint.h>

#define DCH 64        // feature dim
#define KC 512        // codebook entries
#define BLOCK 256
#define HWSZ 4096     // 64*64 spatial
#define SPLIT 2       // codes per position split across SPLIT threads
#define POSB (BLOCK / SPLIT)   // 128 positions per block
#define KHALF (KC / SPLIT)     // 256 codes per thread
#define KG 8          // codes per inner group (8 independent FMA chains)

// numpy pairwise_sum replication for 64 squared terms (fp-contract OFF so
// products round like numpy's elementwise multiply before pairwise add).
__device__ __forceinline__ float pairwise_sq64(const float* __restrict__ a) {
#pragma clang fp contract(off)
  float r0 = a[0] * a[0];
  float r1 = a[1] * a[1];
  float r2 = a[2] * a[2];
  float r3 = a[3] * a[3];
  float r4 = a[4] * a[4];
  float r5 = a[5] * a[5];
  float r6 = a[6] * a[6];
  float r7 = a[7] * a[7];
#pragma unroll
  for (int i = 8; i < 64; i += 8) {
    r0 = r0 + a[i + 0] * a[i + 0];
    r1 = r1 + a[i + 1] * a[i + 1];
    r2 = r2 + a[i + 2] * a[i + 2];
    r3 = r3 + a[i + 3] * a[i + 3];
    r4 = r4 + a[i + 4] * a[i + 4];
    r5 = r5 + a[i + 5] * a[i + 5];
    r6 = r6 + a[i + 6] * a[i + 6];
    r7 = r7 + a[i + 7] * a[i + 7];
  }
  return ((r0 + r1) + (r2 + r3)) + ((r4 + r5) + (r6 + r7));
}

__global__ __launch_bounds__(BLOCK) void vq_argmin_kernel(
    const float* __restrict__ Z,   // (32, 64, 64, 64) = (B, D, H, W)
    const float* __restrict__ W,   // (512, 64)
    int* __restrict__ out) {       // (B*H*W) int32 indices
  __shared__ float wnorm[KC];      // per-code squared norms
  __shared__ float cmin[BLOCK];    // combine buffers
  __shared__ int cidx[BLOCK];

  const int tid = threadIdx.x;
  const int plocal = tid & (POSB - 1);   // position within block
  const int half = tid >> 7;             // which half of the codebook
  const int n = blockIdx.x * POSB + plocal;

  // ---- per-code squared norms, numpy pairwise order (2 codes/thread) ----
#pragma unroll
  for (int c = tid; c < KC; c += BLOCK) {
    wnorm[c] = pairwise_sq64(W + c * DCH);
  }

  // ---- load this position's feature vector into registers ----
  float z[DCH];
  {
    const int b = n >> 12;       // n / 4096
    const int hw = n & 4095;     // n % 4096
    const float* zbase = Z + ((size_t)b * DCH) * HWSZ + hw;
#pragma unroll
    for (int d = 0; d < DCH; ++d) z[d] = zbase[(size_t)d * HWSZ];
  }

  const float znorm = pairwise_sq64(z);
  __syncthreads();

  float bmin = 3.4e38f;
  int bidx = 0;

  // Each thread scans KHALF codes with wave-uniform addresses -> scalar loads.
  const int k0 = half * KHALF;
#pragma unroll 1
  for (int kk = 0; kk < KHALF; kk += KG) {
    const int k = k0 + kk;
    const float* __restrict__ wr = W + (size_t)k * DCH;
    float acc[KG];
#pragma unroll
    for (int j = 0; j < KG; ++j) acc[j] = 0.0f;
#pragma unroll
    for (int d = 0; d < DCH; ++d) {
      const float zd = z[d];
#pragma unroll
      for (int j = 0; j < KG; ++j) {
        acc[j] = fmaf(zd, wr[j * DCH + d], acc[j]);
      }
    }
#pragma unroll
    for (int j = 0; j < KG; ++j) {
      // exact reference order: (znorm - 2*dot) + wnorm
      const float dist = (znorm - 2.0f * acc[j]) + wnorm[k + j];
      if (dist < bmin) { bmin = dist; bidx = k + j; }  // strict <, ascending k
    }
  }

  // ---- combine the two halves (half-1 indices are all larger, so strict <
  //      keeps np.argmin first-min-wins semantics) ----
  cmin[tid] = bmin;
  cidx[tid] = bidx;
  __syncthreads();
  if (half == 0) {
    const float d1 = cmin[tid + POSB];
    const int i1 = cidx[tid + POSB];
    out[n] = (d1 < bmin) ? i1 : bidx;
  }
}

extern "C" void kernel_launch(void* const* d_in, const int* in_sizes, int n_in,
                              void* d_out, int out_size, void* d_ws, size_t ws_size,
                              hipStream_t stream) {
  const float* Z = (const float*)d_in[0];  // (32,64,64,64) fp32
  const float* W = (const float*)d_in[1];  // (512,64) fp32
  int* out = (int*)d_out;                  // int32 indices, B*H*W

  const int npos = in_sizes[0] / DCH;      // 131072
  const int grid = (npos * SPLIT + BLOCK - 1) / BLOCK;  // 1024
  vq_argmin_kernel<<<grid, BLOCK, 0, stream>>>(Z, W, out);
}

// Round 4
// 154.530 us; speedup vs baseline: 3.0408x; 3.0408x over previous
//
#include <hip/hip_runtime.h>
#include <stdint.h>

#define DCH 64        // feature dim
#define KC 512        // codebook entries
#define BLOCK 256
#define HWSZ 4096     // 64*64 spatial
#define SPLIT 4       // codebook quarters, one per wave
#define POSB 64       // positions per block (= lanes per wave)
#define KPART (KC / SPLIT)   // 128 codes per wave
#define KG 8          // codes per inner group (8 independent FMA chains)

// numpy pairwise_sum replication for 64 squared terms (fp-contract OFF so
// products round like numpy's elementwise multiply before pairwise add).
__device__ __forceinline__ float pairwise_sq64(const float* __restrict__ a) {
#pragma clang fp contract(off)
  float r0 = a[0] * a[0];
  float r1 = a[1] * a[1];
  float r2 = a[2] * a[2];
  float r3 = a[3] * a[3];
  float r4 = a[4] * a[4];
  float r5 = a[5] * a[5];
  float r6 = a[6] * a[6];
  float r7 = a[7] * a[7];
#pragma unroll
  for (int i = 8; i < 64; i += 8) {
    r0 = r0 + a[i + 0] * a[i + 0];
    r1 = r1 + a[i + 1] * a[i + 1];
    r2 = r2 + a[i + 2] * a[i + 2];
    r3 = r3 + a[i + 3] * a[i + 3];
    r4 = r4 + a[i + 4] * a[i + 4];
    r5 = r5 + a[i + 5] * a[i + 5];
    r6 = r6 + a[i + 6] * a[i + 6];
    r7 = r7 + a[i + 7] * a[i + 7];
  }
  return ((r0 + r1) + (r2 + r3)) + ((r4 + r5) + (r6 + r7));
}

__global__ __launch_bounds__(BLOCK, 4) void vq_argmin_kernel(
    const float* __restrict__ Z,   // (32, 64, 64, 64) = (B, D, H, W)
    const float* __restrict__ W,   // (512, 64)
    int* __restrict__ out) {       // (B*H*W) int32 indices
  __shared__ float wnorm[KC];          // per-code squared norms
  __shared__ float cmin[SPLIT][POSB];  // per-wave partial mins
  __shared__ int cidx[SPLIT][POSB];    // per-wave partial argmins

  const int tid = threadIdx.x;

  // ---- per-code squared norms, numpy pairwise order ----
  for (int c = tid; c < KC; c += BLOCK) {
    wnorm[c] = pairwise_sq64(W + c * DCH);
  }

  const int lane = tid & 63;
  // Wave index, forced uniform through readfirstlane so the compiler's
  // uniformity analysis keeps all W addresses scalar (s_load path).
  const int wv = __builtin_amdgcn_readfirstlane(tid >> 6);  // 0..3

  const int n = blockIdx.x * POSB + lane;

  // ---- load this position's feature vector into registers ----
  float z[DCH];
  {
    const int b = n >> 12;       // n / 4096
    const int hw = n & 4095;     // n % 4096
    const float* zbase = Z + ((size_t)b * DCH) * HWSZ + hw;
#pragma unroll
    for (int d = 0; d < DCH; ++d) z[d] = zbase[(size_t)d * HWSZ];
  }
  const float znorm = pairwise_sq64(z);
  __syncthreads();

  float bmin = 3.4e38f;
  int bidx = 0;

  // Each wave scans its quarter of the codebook with wave-uniform scalar
  // addresses -> s_load through the scalar cache, v_fmac_f32 v,s,v.
  const int k0 = wv * KPART;
#pragma unroll 1
  for (int kk = 0; kk < KPART; kk += KG) {
    const int k = k0 + kk;
    const float* __restrict__ wr = W + (size_t)k * DCH;
    float acc[KG];
#pragma unroll
    for (int j = 0; j < KG; ++j) acc[j] = 0.0f;
#pragma unroll
    for (int d = 0; d < DCH; ++d) {
      const float zd = z[d];
#pragma unroll
      for (int j = 0; j < KG; ++j) {
        acc[j] = fmaf(zd, wr[j * DCH + d], acc[j]);
      }
    }
#pragma unroll
    for (int j = 0; j < KG; ++j) {
      // exact reference order: (znorm - 2*dot) + wnorm
      const float dist = (znorm - 2.0f * acc[j]) + wnorm[k + j];
      if (dist < bmin) { bmin = dist; bidx = k + j; }  // strict <, ascending k
    }
  }

  cmin[wv][lane] = bmin;
  cidx[wv][lane] = bidx;
  __syncthreads();

  // ---- combine 4 quarters (ascending half order + strict < keeps
  //      np.argmin first-min-wins: ties resolve to the smaller index) ----
  if (tid < POSB) {
    float m = cmin[0][tid];
    int ix = cidx[0][tid];
#pragma unroll
    for (int h = 1; h < SPLIT; ++h) {
      const float mh = cmin[h][tid];
      const int ih = cidx[h][tid];
      if (mh < m) { m = mh; ix = ih; }
    }
    out[blockIdx.x * POSB + tid] = ix;
  }
}

extern "C" void kernel_launch(void* const* d_in, const int* in_sizes, int n_in,
                              void* d_out, int out_size, void* d_ws, size_t ws_size,
                              hipStream_t stream) {
  const float* Z = (const float*)d_in[0];  // (32,64,64,64) fp32
  const float* W = (const float*)d_in[1];  // (512,64) fp32
  int* out = (int*)d_out;                  // int32 indices, B*H*W

  const int npos = in_sizes[0] / DCH;      // 131072
  const int grid = npos / POSB;            // 2048
  vq_argmin_kernel<<<grid, BLOCK, 0, stream>>>(Z, W, out);
}

// Round 5
// 132.741 us; speedup vs baseline: 3.5399x; 1.1641x over previous
//
#include <hip/hip_runtime.h>
#include <stdint.h>

#define DCH 64
#define KC 512
#define HWSZ 4096
#define THETA 1e-4f
#define QCODES 128
#define POSB 64

typedef __attribute__((ext_vector_type(8))) short short8v;
typedef __attribute__((ext_vector_type(4))) float floatx4;

// d_ws layout (bytes)
#define WS_WHS   0                        // 512*64 bf16, swizzled rows
#define WS_WLS   65536
#define WS_WNORM 131072                   // 512 f32 (numpy-pairwise exact)
#define WS_CNT   133120                   // int
#define WS_LIST  133184                   // up to 131072 int
#define WS_NEED  (133184 + 131072 * 4)

__device__ __forceinline__ uint16_t f2bf_rne(float x) {
  uint32_t u = __float_as_uint(x);
  uint32_t r = (u + 0x7fffu + ((u >> 16) & 1u)) >> 16;
  return (uint16_t)r;
}
__device__ __forceinline__ float bf2f(uint16_t b) {
  return __uint_as_float(((uint32_t)b) << 16);
}
// element offset of d within a 64-elem row, 16B-granule XOR swizzle
__device__ __forceinline__ int swz(int row, int d) {
  return (((d >> 3) ^ (row & 7)) << 3) | (d & 7);
}

// numpy pairwise_sum of squares, 64 elems (fp-contract off)
__device__ __forceinline__ float pairwise_sq64(const float* __restrict__ a) {
#pragma clang fp contract(off)
  float r0 = a[0]*a[0], r1 = a[1]*a[1], r2 = a[2]*a[2], r3 = a[3]*a[3];
  float r4 = a[4]*a[4], r5 = a[5]*a[5], r6 = a[6]*a[6], r7 = a[7]*a[7];
#pragma unroll
  for (int i = 8; i < 64; i += 8) {
    r0 += a[i+0]*a[i+0]; r1 += a[i+1]*a[i+1];
    r2 += a[i+2]*a[i+2]; r3 += a[i+3]*a[i+3];
    r4 += a[i+4]*a[i+4]; r5 += a[i+5]*a[i+5];
    r6 += a[i+6]*a[i+6]; r7 += a[i+7]*a[i+7];
  }
  return ((r0+r1)+(r2+r3)) + ((r4+r5)+(r6+r7));
}

// ---------- prep: W -> bf16 split (swizzled) + exact wnorm ----------
__global__ __launch_bounds__(256) void vq_prep(const float* __restrict__ W,
                                               char* __restrict__ ws) {
  const int c = blockIdx.x * 256 + threadIdx.x;
  if (c >= KC) return;
  const float* wr = W + c * DCH;
  ((float*)(ws + WS_WNORM))[c] = pairwise_sq64(wr);
  uint16_t* wh = (uint16_t*)(ws + WS_WHS);
  uint16_t* wl = (uint16_t*)(ws + WS_WLS);
#pragma unroll
  for (int d = 0; d < DCH; ++d) {
    float w = wr[d];
    uint16_t hb = f2bf_rne(w);
    uint16_t lb = f2bf_rne(w - bf2f(hb));
    int so = c * DCH + swz(c, d);
    wh[so] = hb;
    wl[so] = lb;
  }
}

// ---------- main: MFMA scoring + top-2 gap test ----------
__global__ __launch_bounds__(256) void vq_main(const float* __restrict__ Z,
                                               char* __restrict__ ws,
                                               int* __restrict__ out) {
  __shared__ uint16_t zh[POSB * DCH];     // 8 KB
  __shared__ uint16_t zl[POSB * DCH];     // 8 KB
  __shared__ uint16_t wh[QCODES * DCH];   // 16 KB
  __shared__ uint16_t wl[QCODES * DCH];   // 16 KB

  const int tid = threadIdx.x;
  const int lane = tid & 63;
  const int wv = tid >> 6;                // 0..3
  const int nbase = blockIdx.x * POSB;

  const uint16_t* whs = (const uint16_t*)(ws + WS_WHS);
  const uint16_t* wls = (const uint16_t*)(ws + WS_WLS);
  const float* wnorm = (const float*)(ws + WS_WNORM);
  int* cnt = (int*)(ws + WS_CNT);
  int* list = (int*)(ws + WS_LIST);

  // issue quarter-0 W prefetch (ws image is pre-swizzled -> linear copy)
  {
    const char* sh = (const char*)whs;
    const char* sl = (const char*)wls;
#pragma unroll
    for (int r = 0; r < 4; ++r) {
      int base = wv * 1024 + r * 4096;    // wave-uniform LDS dest base
      __builtin_amdgcn_global_load_lds((const uint32_t*)(sh + base + lane * 16),
                                       (uint32_t*)((char*)wh + base), 16, 0, 0);
      __builtin_amdgcn_global_load_lds((const uint32_t*)(sl + base + lane * 16),
                                       (uint32_t*)((char*)wl + base), 16, 0, 0);
    }
  }

  // stage z tile: coalesced read, bf16 split, swizzled LDS write
  {
    const int b = nbase >> 12;
    const int hw0 = nbase & 4095;
#pragma unroll
    for (int i = 0; i < 16; ++i) {
      int flat = tid + i * 256;           // 4096 elems = 64 d x 64 pos
      int d = flat >> 6, po = flat & 63;
      float v = Z[((size_t)b * DCH + d) * HWSZ + hw0 + po];
      uint16_t hb = f2bf_rne(v);
      uint16_t lb = f2bf_rne(v - bf2f(hb));
      int so = po * DCH + swz(po, d);
      zh[so] = hb;
      zl[so] = lb;
    }
  }
  __syncthreads();  // z ready + quarter-0 W ready (implicit vmcnt drain)

  // resident A fragments: row = wv*16 + (lane&15), k = (lane>>4)*8+j per half
  short8v ah[2], al[2];
  {
    const int row = wv * 16 + (lane & 15);
    const int gsub = lane >> 4;
#pragma unroll
    for (int h2 = 0; h2 < 2; ++h2) {
      int go = ((h2 * 4 + gsub) ^ (row & 7)) << 3;
      ah[h2] = *(const short8v*)&zh[row * DCH + go];
      al[h2] = *(const short8v*)&zl[row * DCH + go];
    }
  }

  float m1[4], m2[4];
  int i1[4];
#pragma unroll
  for (int r = 0; r < 4; ++r) { m1[r] = 3.4e38f; m2[r] = 3.4e38f; i1[r] = 0; }

  for (int q = 0; q < 4; ++q) {
    const int csub = lane & 15;
    const int gsub = lane >> 4;
#pragma unroll
    for (int t = 0; t < 8; ++t) {
      const int cloc = t * 16 + csub;
      floatx4 acc = {0.f, 0.f, 0.f, 0.f};
#pragma unroll
      for (int h2 = 0; h2 < 2; ++h2) {
        int go = ((h2 * 4 + gsub) ^ (cloc & 7)) << 3;
        short8v bh = *(const short8v*)&wh[cloc * DCH + go];
        short8v bl = *(const short8v*)&wl[cloc * DCH + go];
        acc = __builtin_amdgcn_mfma_f32_16x16x32_bf16(ah[h2], bh, acc, 0, 0, 0);
        acc = __builtin_amdgcn_mfma_f32_16x16x32_bf16(ah[h2], bl, acc, 0, 0, 0);
        acc = __builtin_amdgcn_mfma_f32_16x16x32_bf16(al[h2], bh, acc, 0, 0, 0);
      }
      const int kglob = q * QCODES + cloc;
      const float wn = wnorm[kglob];
#pragma unroll
      for (int r = 0; r < 4; ++r) {
        float s = fmaf(-2.0f, acc[r], wn);
        bool lt = s < m1[r];
        m2[r] = lt ? m1[r] : fminf(m2[r], s);
        i1[r] = lt ? kglob : i1[r];
        m1[r] = lt ? s : m1[r];
      }
    }
    if (q < 3) {
      __syncthreads();  // everyone done reading this quarter
      const char* sh = (const char*)(whs + (q + 1) * QCODES * DCH);
      const char* sl = (const char*)(wls + (q + 1) * QCODES * DCH);
#pragma unroll
      for (int r = 0; r < 4; ++r) {
        int base = wv * 1024 + r * 4096;
        __builtin_amdgcn_global_load_lds((const uint32_t*)(sh + base + lane * 16),
                                         (uint32_t*)((char*)wh + base), 16, 0, 0);
        __builtin_amdgcn_global_load_lds((const uint32_t*)(sl + base + lane * 16),
                                         (uint32_t*)((char*)wl + base), 16, 0, 0);
      }
      __syncthreads();  // next quarter ready
    }
  }

  // top-2 merge across the 16 lanes sharing each row group
#pragma unroll
  for (int off = 1; off < 16; off <<= 1) {
#pragma unroll
    for (int r = 0; r < 4; ++r) {
      float om1 = __shfl_xor(m1[r], off, 64);
      float om2 = __shfl_xor(m2[r], off, 64);
      int oi = __shfl_xor(i1[r], off, 64);
      float nm2 = fminf(fmaxf(m1[r], om1), fminf(m2[r], om2));
      i1[r] = (om1 < m1[r]) ? oi : i1[r];
      m1[r] = fminf(m1[r], om1);
      m2[r] = nm2;
    }
  }
  if ((lane & 15) == 0) {
    const int g = lane >> 4;
#pragma unroll
    for (int r = 0; r < 4; ++r) {
      int pos = nbase + wv * 16 + g * 4 + r;
      out[pos] = i1[r];
      if (!(m2[r] - m1[r] > THETA)) {   // too close: exact re-score
        int slot = atomicAdd(cnt, 1);
        list[slot] = pos;
      }
    }
  }
}

// ---------- rescue: bit-exact numpy re-score of flagged positions ----------
__global__ __launch_bounds__(256) void vq_rescue(const float* __restrict__ Z,
                                                 const float* __restrict__ W,
                                                 char* __restrict__ ws,
                                                 int* __restrict__ out) {
  const int cnt = *(const int*)(ws + WS_CNT);
  if (cnt == 0) return;
  const int* list = (const int*)(ws + WS_LIST);
  const float* wnorm = (const float*)(ws + WS_WNORM);
  const int lane = threadIdx.x & 63;
  const int wvg = blockIdx.x * 4 + (threadIdx.x >> 6);

  for (int j = wvg; j < cnt; j += 256 * 4) {
    const int pos = list[j];
    const int b = pos >> 12, hw = pos & 4095;
    float z[DCH];
    const float* zb = Z + ((size_t)b * DCH) * HWSZ + hw;
#pragma unroll
    for (int d = 0; d < DCH; ++d) z[d] = zb[(size_t)d * HWSZ];
    const float znorm = pairwise_sq64(z);
    float bm = 3.4e38f;
    int bi = 0;
#pragma unroll 1
    for (int j2 = 0; j2 < 8; ++j2) {
      const int k = j2 * 64 + lane;
      const float* wr = W + (size_t)k * DCH;
      float acc = 0.f;
#pragma unroll
      for (int d = 0; d < DCH; ++d) acc = fmaf(z[d], wr[d], acc);
      float dist = (znorm - 2.0f * acc) + wnorm[k];
      if (dist < bm) { bm = dist; bi = k; }  // ascending k per lane
    }
    // cross-lane argmin, smaller-index-wins on exact ties (numpy rule)
#pragma unroll
    for (int off = 32; off >= 1; off >>= 1) {
      float ov = __shfl_xor(bm, off, 64);
      int oi = __shfl_xor(bi, off, 64);
      if (ov < bm || (ov == bm && oi < bi)) { bm = ov; bi = oi; }
    }
    if (lane == 0) out[pos] = bi;
  }
}

// ---------- fallback (R4, known exact) if ws too small ----------
__global__ __launch_bounds__(256, 4) void vq_fallback(const float* __restrict__ Z,
                                                      const float* __restrict__ W,
                                                      int* __restrict__ out) {
  __shared__ float wnorm[KC];
  __shared__ float cmin[4][64];
  __shared__ int cidx[4][64];
  const int tid = threadIdx.x;
  for (int c = tid; c < KC; c += 256) wnorm[c] = pairwise_sq64(W + c * DCH);
  const int lane = tid & 63;
  const int wv = __builtin_amdgcn_readfirstlane(tid >> 6);
  const int n = blockIdx.x * 64 + lane;
  float z[DCH];
  {
    const int b = n >> 12, hw = n & 4095;
    const float* zbase = Z + ((size_t)b * DCH) * HWSZ + hw;
#pragma unroll
    for (int d = 0; d < DCH; ++d) z[d] = zbase[(size_t)d * HWSZ];
  }
  const float znorm = pairwise_sq64(z);
  __syncthreads();
  float bmin = 3.4e38f;
  int bidx = 0;
  const int k0 = wv * 128;
#pragma unroll 1
  for (int kk = 0; kk < 128; kk += 8) {
    const int k = k0 + kk;
    const float* wr = W + (size_t)k * DCH;
    float acc[8];
#pragma unroll
    for (int j = 0; j < 8; ++j) acc[j] = 0.0f;
#pragma unroll
    for (int d = 0; d < DCH; ++d) {
      const float zd = z[d];
#pragma unroll
      for (int j = 0; j < 8; ++j) acc[j] = fmaf(zd, wr[j * DCH + d], acc[j]);
    }
#pragma unroll
    for (int j = 0; j < 8; ++j) {
      const float dist = (znorm - 2.0f * acc[j]) + wnorm[k + j];
      if (dist < bmin) { bmin = dist; bidx = k + j; }
    }
  }
  cmin[wv][lane] = bmin;
  cidx[wv][lane] = bidx;
  __syncthreads();
  if (tid < 64) {
    float m = cmin[0][tid];
    int ix = cidx[0][tid];
#pragma unroll
    for (int h = 1; h < 4; ++h) {
      if (cmin[h][tid] < m) { m = cmin[h][tid]; ix = cidx[h][tid]; }
    }
    out[blockIdx.x * 64 + tid] = ix;
  }
}

extern "C" void kernel_launch(void* const* d_in, const int* in_sizes, int n_in,
                              void* d_out, int out_size, void* d_ws, size_t ws_size,
                              hipStream_t stream) {
  const float* Z = (const float*)d_in[0];
  const float* W = (const float*)d_in[1];
  int* out = (int*)d_out;
  char* ws = (char*)d_ws;
  const int npos = in_sizes[0] / DCH;  // 131072

  if (ws_size < (size_t)WS_NEED) {
    vq_fallback<<<npos / 64, 256, 0, stream>>>(Z, W, out);
    return;
  }
  hipMemsetAsync(ws + WS_CNT, 0, 4, stream);
  vq_prep<<<2, 256, 0, stream>>>(W, ws);
  vq_main<<<npos / 64, 256, 0, stream>>>(Z, ws, out);
  vq_rescue<<<256, 256, 0, stream>>>(Z, W, ws, out);
}